// Round 9
// baseline (211.618 us; speedup 1.0000x reference)
//
#include <hip/hip_runtime.h>
#include <hip/hip_bf16.h>

#define Bb 4
#define Ss 512
#define Hh 768
#define Dd 24
#define Mm 96
#define Oo 768

typedef __bf16 bf16x8 __attribute__((ext_vector_type(8)));
typedef float f32x4 __attribute__((ext_vector_type(4)));

// ---------------------------------------------------------------------------
// Transpose tile helper: dst[c][r] = bf16(src[r][c]), one 32x32 tile.
// ---------------------------------------------------------------------------
__device__ __forceinline__ void transpose_tile(
    const float* __restrict__ s, __bf16* __restrict__ d,
    int R, int C, int bx, int by, float* smem, int tid)
{
    const int x = tid & 31, y = tid >> 5;
    const int c0 = bx * 32, r0 = by * 32;
    #pragma unroll
    for (int i = 0; i < 4; ++i)
        smem[(y + 8 * i) * 33 + x] = s[(size_t)(r0 + y + 8 * i) * C + c0 + x];
    __syncthreads();
    #pragma unroll
    for (int i = 0; i < 4; ++i)
        d[(size_t)(c0 + y + 8 * i) * R + r0 + x] = (__bf16)smem[x * 33 + (y + 8 * i)];
}

// ---------------------------------------------------------------------------
// prep_kernel: (a) proj -> Zj packed [row][24], Zip padded [row][32]
// (slot24=1, 25..31=0); (b) HiT; (c) Wv1T; (d) Wv2T; (e) Acat seg1 = bf16(Hj);
// (f) WsT[m][x] = Ws1[x][m] fp32.
// blocks: [0,4096) proj | [4096,5632) HiT | [5632,7360) Wv1T |
//         [7360,7936) Wv2T | [7936,8704) hjconv | [8704] WsT
// ---------------------------------------------------------------------------
__global__ __launch_bounds__(256) void prep_kernel(
    const float* __restrict__ Hj, const float* __restrict__ Hi,
    const float* __restrict__ Wpj, const float* __restrict__ Wpi,
    const float* __restrict__ Wv1, const float* __restrict__ Wv2,
    const float* __restrict__ Ws1,
    float* __restrict__ Zj, float* __restrict__ Zip, float* __restrict__ WsT,
    __bf16* __restrict__ HiT, __bf16* __restrict__ Wv1T,
    __bf16* __restrict__ Wv2T, __bf16* __restrict__ Acat)
{
    __shared__ float smem[1088];
    const int bid = blockIdx.x;
    const int tid = threadIdx.x;

    if (bid < 4096) {
        const int row = bid & 2047;
        const int which = bid >> 11;
        const float* src = (which ? Hi : Hj) + (size_t)row * Hh;
        const float* W = which ? Wpi : Wpj;
        float* rowbuf = smem;
        float* partial = smem + 768;
        for (int i = tid; i < Hh; i += 256) rowbuf[i] = src[i];
        __syncthreads();
        if (tid < 192) {
            const int d = tid % Dd;
            const int c = tid / Dd;
            const int h0 = c * 96;
            float s = 0.f;
            #pragma unroll 4
            for (int h = h0; h < h0 + 96; ++h) s = fmaf(rowbuf[h], W[h * Dd + d], s);
            partial[c * Dd + d] = s;
        }
        __syncthreads();
        if (tid < Dd) {
            float s = 0.f;
            #pragma unroll
            for (int c = 0; c < 8; ++c) s += partial[c * Dd + tid];
            if (which) Zip[(size_t)row * 32 + tid] = s;
            else       Zj[(size_t)row * Dd + tid] = s;
        }
        if (which && tid >= Dd && tid < 32)
            Zip[(size_t)row * 32 + tid] = (tid == 24) ? 1.0f : 0.0f;
    } else if (bid < 5632) {
        int rem = bid - 4096;
        const int bz = rem / 384; rem %= 384;
        transpose_tile(Hi + (size_t)bz * Ss * Hh, HiT + (size_t)bz * Hh * Ss,
                       Ss, Hh, rem % 24, rem / 24, smem, tid);
    } else if (bid < 7360) {
        const int rem = bid - 5632;
        transpose_tile(Wv1, Wv1T, 3 * Hh, Oo, rem % 24, rem / 24, smem, tid);
    } else if (bid < 7936) {
        const int rem = bid - 7360;
        transpose_tile(Wv2, Wv2T, Oo, Hh, rem % 24, rem / 24, smem, tid);
    } else if (bid < 8704) {
        const int idx = (bid - 7936) * 256 + tid;
        const int row = idx / 96, c8 = idx % 96;
        const float* s = Hj + (size_t)row * Hh + c8 * 8;
        const float4 u = *(const float4*)s;
        const float4 v = *(const float4*)(s + 4);
        bf16x8 o;
        o[0]=(__bf16)u.x; o[1]=(__bf16)u.y; o[2]=(__bf16)u.z; o[3]=(__bf16)u.w;
        o[4]=(__bf16)v.x; o[5]=(__bf16)v.y; o[6]=(__bf16)v.z; o[7]=(__bf16)v.w;
        *(bf16x8*)&Acat[(size_t)row * 2304 + Hh + c8 * 8] = o;
    } else {
        // WsT 96x96 transpose via LDS (single block)
        __shared__ float W[96 * 97];
        for (int i = tid; i < 96 * 96; i += 256) W[(i / 96) * 97 + (i % 96)] = Ws1[i];
        __syncthreads();
        for (int i = tid; i < 96 * 96; i += 256) WsT[i] = W[(i % 96) * 97 + (i / 96)];
    }
}

// ---------------------------------------------------------------------------
// wprep: one block per p. Bw[p][m][k] bf16, k in [0,64):
//   k<24: Zj[p,k]*W1h[k][m] + W1i[k][m]   | k==24: tj[p][m]+bs1[m]
//   25..31: 0 | 32..55: W1d[k-32][m] | 56..63: 0
// Items (m,k8): m=i>>3, k8=i&7 -> writes k-contiguous (coalesced),
// reads WsT[m][...] (consecutive threads -> consecutive addresses).
// ---------------------------------------------------------------------------
__global__ __launch_bounds__(256) void wprep_kernel(
    const float* __restrict__ Zj, const float* __restrict__ WsT,
    const float* __restrict__ bs1, __bf16* __restrict__ Bw)
{
    const int p = blockIdx.x;
    const int tid = threadIdx.x;
    __shared__ float zj[Dd];
    if (tid < Dd) zj[tid] = Zj[(size_t)p * Dd + tid];
    __syncthreads();
    #pragma unroll
    for (int i = tid; i < 768; i += 256) {
        const int m = i >> 3, k8 = i & 7;
        const int k0 = k8 * 8;
        const float* wr = WsT + (size_t)m * 96;
        bf16x8 o;
        if (k8 < 3) {
            #pragma unroll
            for (int j = 0; j < 8; ++j) {
                const int k = k0 + j;
                o[j] = (__bf16)fmaf(zj[k], wr[48 + k], wr[24 + k]);
            }
        } else if (k8 == 3) {
            float tj = bs1[m];
            #pragma unroll
            for (int d = 0; d < Dd; ++d) tj = fmaf(zj[d], wr[d], tj);
            o[0] = (__bf16)tj;
            #pragma unroll
            for (int j = 1; j < 8; ++j) o[j] = (__bf16)0.f;
        } else if (k8 < 7) {
            #pragma unroll
            for (int j = 0; j < 8; ++j) o[j] = (__bf16)wr[72 + (k0 - 32) + j];
        } else {
            #pragma unroll
            for (int j = 0; j < 8; ++j) o[j] = (__bf16)0.f;
        }
        *(bf16x8*)(Bw + (((size_t)p * 96 + m) << 6) + k0) = o;
    }
}

// ---------------------------------------------------------------------------
// pair_kernel: per (b,p) block, logits over 512 q + softmax -> bf16 probs.
// A = Bw[p] fragments (12 contiguous 16B loads, zero build cost);
// B = Zip fragments (coalesced 2KB wave loads, prefetched one t ahead).
// In-lane m-reduction + 2 shfl; R4 block softmax.
// ---------------------------------------------------------------------------
__global__ __launch_bounds__(256) void pair_kernel(
    const float* __restrict__ Zj, const float* __restrict__ Zip,
    const __bf16* __restrict__ Bw, const float* __restrict__ ws2,
    const float* __restrict__ bs2p, const int* __restrict__ mask,
    __bf16* __restrict__ probs)
{
    const int bp = blockIdx.x;
    const int b  = bp >> 9;              // S = 512
    const int tid  = threadIdx.x;
    const int lane = tid & 63;
    const int wid  = tid >> 6;
    const int col  = lane & 15;          // A: m-row / B: q-col
    const int g    = lane >> 4;          // k-quad

    __shared__ float logitsl[Ss];
    __shared__ float red[8];

    // A-fragments straight from Bw (no construction)
    bf16x8 aw[6][2];
    #pragma unroll
    for (int n = 0; n < 6; ++n) {
        const __bf16* base = Bw + (((size_t)bp * 96 + n * 16 + col) << 6) + g * 8;
        aw[n][0] = *(const bf16x8*)(base);
        aw[n][1] = *(const bf16x8*)(base + 32);
    }
    float ws2r[6][4];
    #pragma unroll
    for (int n = 0; n < 6; ++n) {
        const float4 w4 = *(const float4*)&ws2[n * 16 + g * 4];
        ws2r[n][0] = w4.x; ws2r[n][1] = w4.y; ws2r[n][2] = w4.z; ws2r[n][3] = w4.w;
    }

    float zj8[8];
    if (g < 3) {
        const float* zr = Zj + (size_t)bp * Dd + g * 8;
        const float4 u = *(const float4*)zr;
        const float4 v = *(const float4*)(zr + 4);
        zj8[0]=u.x; zj8[1]=u.y; zj8[2]=u.z; zj8[3]=u.w;
        zj8[4]=v.x; zj8[5]=v.y; zj8[6]=v.z; zj8[7]=v.w;
    } else {
        #pragma unroll
        for (int j = 0; j < 8; ++j) zj8[j] = 0.f;
    }

    // B source: Zip [row][32]; g==3 slots = [1,0..0] pair with bias row /
    // zero weights -> branch-free.
    const float* zb = Zip + ((size_t)(b * Ss + wid * 128 + col) * 32) + g * 8;

    float4 cu = *(const float4*)zb;
    float4 cv = *(const float4*)(zb + 4);

    for (int t = 0; t < 8; ++t) {
        const float4 u = cu, v = cv;
        if (t + 1 < 8) {
            const float* zr = zb + (size_t)(t + 1) * 16 * 32;
            cu = *(const float4*)zr; cv = *(const float4*)(zr + 4);
        }
        bf16x8 b0, b1;
        b0[0]=(__bf16)u.x; b0[1]=(__bf16)u.y; b0[2]=(__bf16)u.z; b0[3]=(__bf16)u.w;
        b0[4]=(__bf16)v.x; b0[5]=(__bf16)v.y; b0[6]=(__bf16)v.z; b0[7]=(__bf16)v.w;
        b1[0]=(__bf16)fabsf(zj8[0]-u.x); b1[1]=(__bf16)fabsf(zj8[1]-u.y);
        b1[2]=(__bf16)fabsf(zj8[2]-u.z); b1[3]=(__bf16)fabsf(zj8[3]-u.w);
        b1[4]=(__bf16)fabsf(zj8[4]-v.x); b1[5]=(__bf16)fabsf(zj8[5]-v.y);
        b1[6]=(__bf16)fabsf(zj8[6]-v.z); b1[7]=(__bf16)fabsf(zj8[7]-v.w);

        f32x4 acc[6];
        #pragma unroll
        for (int n = 0; n < 6; ++n) acc[n] = (f32x4){0.f, 0.f, 0.f, 0.f};
        #pragma unroll
        for (int n = 0; n < 6; ++n) {
            acc[n] = __builtin_amdgcn_mfma_f32_16x16x32_bf16(aw[n][0], b0, acc[n], 0, 0, 0);
            acc[n] = __builtin_amdgcn_mfma_f32_16x16x32_bf16(aw[n][1], b1, acc[n], 0, 0, 0);
        }

        float lsum = 0.f;
        #pragma unroll
        for (int n = 0; n < 6; ++n)
            #pragma unroll
            for (int r = 0; r < 4; ++r)
                lsum = fmaf(fmaxf(acc[n][r], 0.f), ws2r[n][r], lsum);
        lsum += __shfl_xor(lsum, 16);
        lsum += __shfl_xor(lsum, 32);
        if (lane < 16) logitsl[wid * 128 + t * 16 + lane] = lsum;
    }
    __syncthreads();

    const float bs2v = bs2p[0];
    const int* mrow = mask + (size_t)b * Ss;
    float l0 = logitsl[tid]       + bs2v + (1.0f - (float)mrow[tid])       * (-3.402823466e+38f);
    float l1 = logitsl[tid + 256] + bs2v + (1.0f - (float)mrow[tid + 256]) * (-3.402823466e+38f);
    float vmax = fmaxf(l0, l1);
    #pragma unroll
    for (int off = 32; off > 0; off >>= 1) vmax = fmaxf(vmax, __shfl_xor(vmax, off));
    if (lane == 0) red[wid] = vmax;
    __syncthreads();
    const float mx = fmaxf(fmaxf(red[0], red[1]), fmaxf(red[2], red[3]));
    const float e0 = __expf(l0 - mx);
    const float e1 = __expf(l1 - mx);
    float vs = e0 + e1;
    #pragma unroll
    for (int off = 32; off > 0; off >>= 1) vs += __shfl_xor(vs, off);
    if (lane == 0) red[4 + wid] = vs;
    __syncthreads();
    const float inv = 1.0f / (red[4] + red[5] + red[6] + red[7]);
    __bf16* prow = probs + (size_t)bp * Ss;
    prow[tid] = (__bf16)(e0 * inv);
    prow[tid + 256] = (__bf16)(e1 * inv);
}

// ---------------------------------------------------------------------------
// bf16 MFMA GEMM (exact R4/R8 version), 64x64 tile, BK=64, LDS single-buffer
// + register prefetch. MODE 0: ctx -> Acat seg0 & seg2. MODE 1: mhid.
// MODE 2: out = alpha*(mhid@Wv2T+bv2).
// ---------------------------------------------------------------------------
template<int MODE>
__global__ __launch_bounds__(256) void gemm_kernel(
    const __bf16* __restrict__ A, const __bf16* __restrict__ Bt,
    const float* __restrict__ Hjf, const float* __restrict__ bias,
    const float* __restrict__ alphap,
    __bf16* __restrict__ obf, float* __restrict__ of)
{
    constexpr int K = (MODE == 0) ? 512 : (MODE == 1) ? 2304 : 768;
    constexpr int NIT = K / 64;
    constexpr int LDT = 72;

    __shared__ __bf16 As[64 * LDT];
    __shared__ __bf16 Bs[64 * LDT];

    const int tid = threadIdx.x;
    const int lane = tid & 63;
    const int wid = tid >> 6;
    const int col = lane & 15, g = lane >> 4;
    const int wm = wid >> 1, wn = wid & 1;
    const int r0 = blockIdx.x * 64;
    const int n0 = blockIdx.y * 64;
    const __bf16* Btb = (MODE == 0) ? Bt + (size_t)(r0 >> 9) * (Hh * Ss) : Bt;

    const int srow = tid >> 2;
    const int sc8  = (tid & 3) * 16;
    const __bf16* ag = A   + (size_t)(r0 + srow) * K + sc8;
    const __bf16* bg = Btb + (size_t)(n0 + srow) * K + sc8;
    __bf16* asl = &As[srow * LDT + sc8];
    __bf16* bsl = &Bs[srow * LDT + sc8];

    bf16x8 ra0 = *(const bf16x8*)(ag);
    bf16x8 ra1 = *(const bf16x8*)(ag + 8);
    bf16x8 rb0 = *(const bf16x8*)(bg);
    bf16x8 rb1 = *(const bf16x8*)(bg + 8);

    f32x4 acc[2][2];
    #pragma unroll
    for (int mi = 0; mi < 2; ++mi)
        #pragma unroll
        for (int ni = 0; ni < 2; ++ni) acc[mi][ni] = (f32x4){0.f, 0.f, 0.f, 0.f};

    for (int it = 0; it < NIT; ++it) {
        __syncthreads();
        *(bf16x8*)(asl)     = ra0;
        *(bf16x8*)(asl + 8) = ra1;
        *(bf16x8*)(bsl)     = rb0;
        *(bf16x8*)(bsl + 8) = rb1;
        __syncthreads();
        if (it + 1 < NIT) {
            const int kk = (it + 1) * 64;
            ra0 = *(const bf16x8*)(ag + kk);
            ra1 = *(const bf16x8*)(ag + kk + 8);
            rb0 = *(const bf16x8*)(bg + kk);
            rb1 = *(const bf16x8*)(bg + kk + 8);
        }
        #pragma unroll
        for (int h = 0; h < 2; ++h) {
            bf16x8 a0 = *(const bf16x8*)&As[(wm * 32 + col)      * LDT + h * 32 + g * 8];
            bf16x8 a1 = *(const bf16x8*)&As[(wm * 32 + 16 + col) * LDT + h * 32 + g * 8];
            bf16x8 b0 = *(const bf16x8*)&Bs[(wn * 32 + col)      * LDT + h * 32 + g * 8];
            bf16x8 b1 = *(const bf16x8*)&Bs[(wn * 32 + 16 + col) * LDT + h * 32 + g * 8];
            acc[0][0] = __builtin_amdgcn_mfma_f32_16x16x32_bf16(a0, b0, acc[0][0], 0, 0, 0);
            acc[0][1] = __builtin_amdgcn_mfma_f32_16x16x32_bf16(a0, b1, acc[0][1], 0, 0, 0);
            acc[1][0] = __builtin_amdgcn_mfma_f32_16x16x32_bf16(a1, b0, acc[1][0], 0, 0, 0);
            acc[1][1] = __builtin_amdgcn_mfma_f32_16x16x32_bf16(a1, b1, acc[1][1], 0, 0, 0);
        }
    }

    const float al = (MODE == 2) ? alphap[0] : 0.f;
    #pragma unroll
    for (int mi = 0; mi < 2; ++mi) {
        #pragma unroll
        for (int r = 0; r < 4; ++r) {
            const int row = r0 + wm * 32 + mi * 16 + g * 4 + r;
            #pragma unroll
            for (int ni = 0; ni < 2; ++ni) {
                const int cn = n0 + wn * 32 + ni * 16 + col;
                const float v = acc[mi][ni][r];
                if (MODE == 0) {
                    const float hjv = Hjf[(size_t)row * Hh + cn];
                    obf[(size_t)row * 2304 + cn] = (__bf16)v;
                    obf[(size_t)row * 2304 + 1536 + cn] = (__bf16)(v * hjv);
                } else if (MODE == 1) {
                    obf[(size_t)row * Oo + cn] = (__bf16)fmaxf(v + bias[cn], 0.f);
                } else {
                    of[(size_t)row * Hh + cn] = al * (v + bias[cn]);
                }
            }
        }
    }
}

// ---------------------------------------------------------------------------
extern "C" void kernel_launch(void* const* d_in, const int* in_sizes, int n_in,
                              void* d_out, int out_size, void* d_ws, size_t ws_size,
                              hipStream_t stream)
{
    const float* Hj  = (const float*)d_in[0];
    const float* Hi  = (const float*)d_in[1];
    const float* Wpj = (const float*)d_in[2];
    const float* Wpi = (const float*)d_in[3];
    const float* Ws1 = (const float*)d_in[4];
    const float* bs1 = (const float*)d_in[5];
    const float* ws2 = (const float*)d_in[6];
    const float* bs2 = (const float*)d_in[7];
    const float* Wv1 = (const float*)d_in[8];
    const float* bv1 = (const float*)d_in[9];
    const float* Wv2 = (const float*)d_in[10];
    const float* bv2 = (const float*)d_in[11];
    const float* alpha = (const float*)d_in[12];
    const int* mask  = (const int*)d_in[13];

    // workspace (float units) — all regions distinct
    float* ws = (float*)d_ws;
    float* Zj      = ws;                  // 49152
    float* Zip     = Zj + 49152;          // 65536  (2048x32 padded)
    float* WsT     = Zip + 65536;         // 9216
    float* probs_f = WsT + 9216;          // 524288
    float* HiT_f   = probs_f + 524288;    // 786432
    float* Wv2T_f  = HiT_f + 786432;      // 294912
    float* mhid_f  = Wv2T_f + 294912;     // 786432
    float* Acat_f  = mhid_f + 786432;     // 2359296
    float* Wv1T_f  = Acat_f + 2359296;    // 884736
    float* Bw_f    = Wv1T_f + 884736;     // 6291456 (25 MB bf16)
    // total ~48.2 MB

    __bf16* probs_bf = (__bf16*)probs_f;  // [2048][512]
    __bf16* HiT      = (__bf16*)HiT_f;    // [4][768][512]
    __bf16* Wv2T     = (__bf16*)Wv2T_f;   // [768][768]
    __bf16* mhid_bf  = (__bf16*)mhid_f;   // [2048][768]
    __bf16* Acat     = (__bf16*)Acat_f;   // [2048][2304]
    __bf16* Wv1T     = (__bf16*)Wv1T_f;   // [768][2304]
    __bf16* Bw       = (__bf16*)Bw_f;     // [2048][96][64]

    prep_kernel<<<dim3(8705), 256, 0, stream>>>(
        Hj, Hi, Wpj, Wpi, Wv1, Wv2, Ws1, Zj, Zip, WsT, HiT, Wv1T, Wv2T, Acat);
    wprep_kernel<<<dim3(2048), 256, 0, stream>>>(Zj, WsT, bs1, Bw);
    pair_kernel<<<dim3(Bb * Ss), 256, 0, stream>>>(
        Zj, Zip, Bw, ws2, bs2, mask, probs_bf);
    gemm_kernel<0><<<dim3(2048 / 64, Hh / 64), 256, 0, stream>>>(
        probs_bf, HiT, Hj, nullptr, nullptr, Acat, nullptr);
    gemm_kernel<1><<<dim3(2048 / 64, Oo / 64), 256, 0, stream>>>(
        Acat, Wv1T, nullptr, bv1, nullptr, mhid_bf, nullptr);
    gemm_kernel<2><<<dim3(2048 / 64, Hh / 64), 256, 0, stream>>>(
        mhid_bf, Wv2T, nullptr, bv2, alpha, nullptr, (float*)d_out);
}

// Round 10
// 193.223 us; speedup vs baseline: 1.0952x; 1.0952x over previous
//
#include <hip/hip_runtime.h>
#include <hip/hip_bf16.h>

#define Bb 4
#define Ss 512
#define Hh 768
#define Dd 24
#define Mm 96
#define Oo 768

typedef __bf16 bf16x8 __attribute__((ext_vector_type(8)));
typedef float f32x4 __attribute__((ext_vector_type(4)));

// ---------------------------------------------------------------------------
// Transpose tile helpers (32x32 via padded smem)
// ---------------------------------------------------------------------------
__device__ __forceinline__ void transpose_tile(
    const float* __restrict__ s, __bf16* __restrict__ d,
    int R, int C, int bx, int by, float* smem, int tid)
{
    const int x = tid & 31, y = tid >> 5;
    const int c0 = bx * 32, r0 = by * 32;
    #pragma unroll
    for (int i = 0; i < 4; ++i)
        smem[(y + 8 * i) * 33 + x] = s[(size_t)(r0 + y + 8 * i) * C + c0 + x];
    __syncthreads();
    #pragma unroll
    for (int i = 0; i < 4; ++i)
        d[(size_t)(c0 + y + 8 * i) * R + r0 + x] = (__bf16)smem[x * 33 + (y + 8 * i)];
}

__device__ __forceinline__ void transpose_tile_f32(
    const float* __restrict__ s, float* __restrict__ d,
    int R, int C, int bx, int by, float* smem, int tid)
{
    const int x = tid & 31, y = tid >> 5;
    const int c0 = bx * 32, r0 = by * 32;
    #pragma unroll
    for (int i = 0; i < 4; ++i)
        smem[(y + 8 * i) * 33 + x] = s[(size_t)(r0 + y + 8 * i) * C + c0 + x];
    __syncthreads();
    #pragma unroll
    for (int i = 0; i < 4; ++i)
        d[(size_t)(c0 + y + 8 * i) * R + r0 + x] = smem[x * 33 + (y + 8 * i)];
}

// ---------------------------------------------------------------------------
// prep_kernel: (a) proj -> Zj packed [row][24], Zip padded [row][32]
// (slot24=1, 25..31=0); (b) HiT; (c) Wv1T; (d) Wv2T; (e) Acat seg1 = bf16(Hj);
// (f) WsT[m][x] = Ws1[x][m] fp32 via 3x3 32-tiles (smem only — NO large
// static LDS: R9's 37KB W[] array capped occupancy chip-wide).
// blocks: [0,4096) proj | [4096,5632) HiT | [5632,7360) Wv1T |
//         [7360,7936) Wv2T | [7936,8704) hjconv | [8704,8713) WsT
// ---------------------------------------------------------------------------
__global__ __launch_bounds__(256) void prep_kernel(
    const float* __restrict__ Hj, const float* __restrict__ Hi,
    const float* __restrict__ Wpj, const float* __restrict__ Wpi,
    const float* __restrict__ Wv1, const float* __restrict__ Wv2,
    const float* __restrict__ Ws1,
    float* __restrict__ Zj, float* __restrict__ Zip, float* __restrict__ WsT,
    __bf16* __restrict__ HiT, __bf16* __restrict__ Wv1T,
    __bf16* __restrict__ Wv2T, __bf16* __restrict__ Acat)
{
    __shared__ float smem[1088];
    const int bid = blockIdx.x;
    const int tid = threadIdx.x;

    if (bid < 4096) {
        const int row = bid & 2047;
        const int which = bid >> 11;
        const float* src = (which ? Hi : Hj) + (size_t)row * Hh;
        const float* W = which ? Wpi : Wpj;
        float* rowbuf = smem;
        float* partial = smem + 768;
        for (int i = tid; i < Hh; i += 256) rowbuf[i] = src[i];
        __syncthreads();
        if (tid < 192) {
            const int d = tid % Dd;
            const int c = tid / Dd;
            const int h0 = c * 96;
            float s = 0.f;
            #pragma unroll 4
            for (int h = h0; h < h0 + 96; ++h) s = fmaf(rowbuf[h], W[h * Dd + d], s);
            partial[c * Dd + d] = s;
        }
        __syncthreads();
        if (tid < Dd) {
            float s = 0.f;
            #pragma unroll
            for (int c = 0; c < 8; ++c) s += partial[c * Dd + tid];
            if (which) Zip[(size_t)row * 32 + tid] = s;
            else       Zj[(size_t)row * Dd + tid] = s;
        }
        if (which && tid >= Dd && tid < 32)
            Zip[(size_t)row * 32 + tid] = (tid == 24) ? 1.0f : 0.0f;
    } else if (bid < 5632) {
        int rem = bid - 4096;
        const int bz = rem / 384; rem %= 384;
        transpose_tile(Hi + (size_t)bz * Ss * Hh, HiT + (size_t)bz * Hh * Ss,
                       Ss, Hh, rem % 24, rem / 24, smem, tid);
    } else if (bid < 7360) {
        const int rem = bid - 5632;
        transpose_tile(Wv1, Wv1T, 3 * Hh, Oo, rem % 24, rem / 24, smem, tid);
    } else if (bid < 7936) {
        const int rem = bid - 7360;
        transpose_tile(Wv2, Wv2T, Oo, Hh, rem % 24, rem / 24, smem, tid);
    } else if (bid < 8704) {
        const int idx = (bid - 7936) * 256 + tid;
        const int row = idx / 96, c8 = idx % 96;
        const float* s = Hj + (size_t)row * Hh + c8 * 8;
        const float4 u = *(const float4*)s;
        const float4 v = *(const float4*)(s + 4);
        bf16x8 o;
        o[0]=(__bf16)u.x; o[1]=(__bf16)u.y; o[2]=(__bf16)u.z; o[3]=(__bf16)u.w;
        o[4]=(__bf16)v.x; o[5]=(__bf16)v.y; o[6]=(__bf16)v.z; o[7]=(__bf16)v.w;
        *(bf16x8*)&Acat[(size_t)row * 2304 + Hh + c8 * 8] = o;
    } else {
        // WsT[m][x] = Ws1[x][m]: 96x96 fp32 as 3x3 tiles of 32
        const int rem = bid - 8704;
        transpose_tile_f32(Ws1, WsT, 96, 96, rem % 3, rem / 3, smem, tid);
    }
}

// ---------------------------------------------------------------------------
// wprep: one block per p. Bw[p][m][k] bf16, k in [0,64):
//   k<24: Zj[p,k]*W1h[k][m] + W1i[k][m]   | k==24: tj[p][m]+bs1[m]
//   25..31: 0 | 32..55: W1d[k-32][m] | 56..63: 0
// ---------------------------------------------------------------------------
__global__ __launch_bounds__(256) void wprep_kernel(
    const float* __restrict__ Zj, const float* __restrict__ WsT,
    const float* __restrict__ bs1, __bf16* __restrict__ Bw)
{
    const int p = blockIdx.x;
    const int tid = threadIdx.x;
    __shared__ float zj[Dd];
    if (tid < Dd) zj[tid] = Zj[(size_t)p * Dd + tid];
    __syncthreads();
    #pragma unroll
    for (int i = tid; i < 768; i += 256) {
        const int m = i >> 3, k8 = i & 7;
        const int k0 = k8 * 8;
        const float* wr = WsT + (size_t)m * 96;
        bf16x8 o;
        if (k8 < 3) {
            #pragma unroll
            for (int j = 0; j < 8; ++j) {
                const int k = k0 + j;
                o[j] = (__bf16)fmaf(zj[k], wr[48 + k], wr[24 + k]);
            }
        } else if (k8 == 3) {
            float tj = bs1[m];
            #pragma unroll
            for (int d = 0; d < Dd; ++d) tj = fmaf(zj[d], wr[d], tj);
            o[0] = (__bf16)tj;
            #pragma unroll
            for (int j = 1; j < 8; ++j) o[j] = (__bf16)0.f;
        } else if (k8 < 7) {
            #pragma unroll
            for (int j = 0; j < 8; ++j) o[j] = (__bf16)wr[72 + (k0 - 32) + j];
        } else {
            #pragma unroll
            for (int j = 0; j < 8; ++j) o[j] = (__bf16)0.f;
        }
        *(bf16x8*)(Bw + (((size_t)p * 96 + m) << 6) + k0) = o;
    }
}

// ---------------------------------------------------------------------------
// pair_kernel: per (b,p) block, logits over 512 q + softmax -> bf16 probs.
// A = Bw[p] fragments (12 contiguous 16B loads); B = Zip fragments
// (coalesced 2KB wave loads, prefetched one t ahead). In-lane m-reduction.
// ---------------------------------------------------------------------------
__global__ __launch_bounds__(256) void pair_kernel(
    const float* __restrict__ Zj, const float* __restrict__ Zip,
    const __bf16* __restrict__ Bw, const float* __restrict__ ws2,
    const float* __restrict__ bs2p, const int* __restrict__ mask,
    __bf16* __restrict__ probs)
{
    const int bp = blockIdx.x;
    const int b  = bp >> 9;              // S = 512
    const int tid  = threadIdx.x;
    const int lane = tid & 63;
    const int wid  = tid >> 6;
    const int col  = lane & 15;          // A: m-row / B: q-col
    const int g    = lane >> 4;          // k-quad

    __shared__ float logitsl[Ss];
    __shared__ float red[8];

    bf16x8 aw[6][2];
    #pragma unroll
    for (int n = 0; n < 6; ++n) {
        const __bf16* base = Bw + (((size_t)bp * 96 + n * 16 + col) << 6) + g * 8;
        aw[n][0] = *(const bf16x8*)(base);
        aw[n][1] = *(const bf16x8*)(base + 32);
    }
    float ws2r[6][4];
    #pragma unroll
    for (int n = 0; n < 6; ++n) {
        const float4 w4 = *(const float4*)&ws2[n * 16 + g * 4];
        ws2r[n][0] = w4.x; ws2r[n][1] = w4.y; ws2r[n][2] = w4.z; ws2r[n][3] = w4.w;
    }

    float zj8[8];
    if (g < 3) {
        const float* zr = Zj + (size_t)bp * Dd + g * 8;
        const float4 u = *(const float4*)zr;
        const float4 v = *(const float4*)(zr + 4);
        zj8[0]=u.x; zj8[1]=u.y; zj8[2]=u.z; zj8[3]=u.w;
        zj8[4]=v.x; zj8[5]=v.y; zj8[6]=v.z; zj8[7]=v.w;
    } else {
        #pragma unroll
        for (int j = 0; j < 8; ++j) zj8[j] = 0.f;
    }

    const float* zb = Zip + ((size_t)(b * Ss + wid * 128 + col) * 32) + g * 8;

    float4 cu = *(const float4*)zb;
    float4 cv = *(const float4*)(zb + 4);

    for (int t = 0; t < 8; ++t) {
        const float4 u = cu, v = cv;
        if (t + 1 < 8) {
            const float* zr = zb + (size_t)(t + 1) * 16 * 32;
            cu = *(const float4*)zr; cv = *(const float4*)(zr + 4);
        }
        bf16x8 b0, b1;
        b0[0]=(__bf16)u.x; b0[1]=(__bf16)u.y; b0[2]=(__bf16)u.z; b0[3]=(__bf16)u.w;
        b0[4]=(__bf16)v.x; b0[5]=(__bf16)v.y; b0[6]=(__bf16)v.z; b0[7]=(__bf16)v.w;
        b1[0]=(__bf16)fabsf(zj8[0]-u.x); b1[1]=(__bf16)fabsf(zj8[1]-u.y);
        b1[2]=(__bf16)fabsf(zj8[2]-u.z); b1[3]=(__bf16)fabsf(zj8[3]-u.w);
        b1[4]=(__bf16)fabsf(zj8[4]-v.x); b1[5]=(__bf16)fabsf(zj8[5]-v.y);
        b1[6]=(__bf16)fabsf(zj8[6]-v.z); b1[7]=(__bf16)fabsf(zj8[7]-v.w);

        f32x4 acc[6];
        #pragma unroll
        for (int n = 0; n < 6; ++n) acc[n] = (f32x4){0.f, 0.f, 0.f, 0.f};
        #pragma unroll
        for (int n = 0; n < 6; ++n) {
            acc[n] = __builtin_amdgcn_mfma_f32_16x16x32_bf16(aw[n][0], b0, acc[n], 0, 0, 0);
            acc[n] = __builtin_amdgcn_mfma_f32_16x16x32_bf16(aw[n][1], b1, acc[n], 0, 0, 0);
        }

        float lsum = 0.f;
        #pragma unroll
        for (int n = 0; n < 6; ++n)
            #pragma unroll
            for (int r = 0; r < 4; ++r)
                lsum = fmaf(fmaxf(acc[n][r], 0.f), ws2r[n][r], lsum);
        lsum += __shfl_xor(lsum, 16);
        lsum += __shfl_xor(lsum, 32);
        if (lane < 16) logitsl[wid * 128 + t * 16 + lane] = lsum;
    }
    __syncthreads();

    const float bs2v = bs2p[0];
    const int* mrow = mask + (size_t)b * Ss;
    float l0 = logitsl[tid]       + bs2v + (1.0f - (float)mrow[tid])       * (-3.402823466e+38f);
    float l1 = logitsl[tid + 256] + bs2v + (1.0f - (float)mrow[tid + 256]) * (-3.402823466e+38f);
    float vmax = fmaxf(l0, l1);
    #pragma unroll
    for (int off = 32; off > 0; off >>= 1) vmax = fmaxf(vmax, __shfl_xor(vmax, off));
    if (lane == 0) red[wid] = vmax;
    __syncthreads();
    const float mx = fmaxf(fmaxf(red[0], red[1]), fmaxf(red[2], red[3]));
    const float e0 = __expf(l0 - mx);
    const float e1 = __expf(l1 - mx);
    float vs = e0 + e1;
    #pragma unroll
    for (int off = 32; off > 0; off >>= 1) vs += __shfl_xor(vs, off);
    if (lane == 0) red[4 + wid] = vs;
    __syncthreads();
    const float inv = 1.0f / (red[4] + red[5] + red[6] + red[7]);
    __bf16* prow = probs + (size_t)bp * Ss;
    prow[tid] = (__bf16)(e0 * inv);
    prow[tid + 256] = (__bf16)(e1 * inv);
}

// ---------------------------------------------------------------------------
// bf16 MFMA GEMM (exact R4/R8 version), 64x64 tile, BK=64, LDS single-buffer
// + register prefetch. MODE 0: ctx -> Acat seg0 & seg2. MODE 1: mhid.
// MODE 2: out = alpha*(mhid@Wv2T+bv2).
// ---------------------------------------------------------------------------
template<int MODE>
__global__ __launch_bounds__(256) void gemm_kernel(
    const __bf16* __restrict__ A, const __bf16* __restrict__ Bt,
    const float* __restrict__ Hjf, const float* __restrict__ bias,
    const float* __restrict__ alphap,
    __bf16* __restrict__ obf, float* __restrict__ of)
{
    constexpr int K = (MODE == 0) ? 512 : (MODE == 1) ? 2304 : 768;
    constexpr int NIT = K / 64;
    constexpr int LDT = 72;

    __shared__ __bf16 As[64 * LDT];
    __shared__ __bf16 Bs[64 * LDT];

    const int tid = threadIdx.x;
    const int lane = tid & 63;
    const int wid = tid >> 6;
    const int col = lane & 15, g = lane >> 4;
    const int wm = wid >> 1, wn = wid & 1;
    const int r0 = blockIdx.x * 64;
    const int n0 = blockIdx.y * 64;
    const __bf16* Btb = (MODE == 0) ? Bt + (size_t)(r0 >> 9) * (Hh * Ss) : Bt;

    const int srow = tid >> 2;
    const int sc8  = (tid & 3) * 16;
    const __bf16* ag = A   + (size_t)(r0 + srow) * K + sc8;
    const __bf16* bg = Btb + (size_t)(n0 + srow) * K + sc8;
    __bf16* asl = &As[srow * LDT + sc8];
    __bf16* bsl = &Bs[srow * LDT + sc8];

    bf16x8 ra0 = *(const bf16x8*)(ag);
    bf16x8 ra1 = *(const bf16x8*)(ag + 8);
    bf16x8 rb0 = *(const bf16x8*)(bg);
    bf16x8 rb1 = *(const bf16x8*)(bg + 8);

    f32x4 acc[2][2];
    #pragma unroll
    for (int mi = 0; mi < 2; ++mi)
        #pragma unroll
        for (int ni = 0; ni < 2; ++ni) acc[mi][ni] = (f32x4){0.f, 0.f, 0.f, 0.f};

    for (int it = 0; it < NIT; ++it) {
        __syncthreads();
        *(bf16x8*)(asl)     = ra0;
        *(bf16x8*)(asl + 8) = ra1;
        *(bf16x8*)(bsl)     = rb0;
        *(bf16x8*)(bsl + 8) = rb1;
        __syncthreads();
        if (it + 1 < NIT) {
            const int kk = (it + 1) * 64;
            ra0 = *(const bf16x8*)(ag + kk);
            ra1 = *(const bf16x8*)(ag + kk + 8);
            rb0 = *(const bf16x8*)(bg + kk);
            rb1 = *(const bf16x8*)(bg + kk + 8);
        }
        #pragma unroll
        for (int h = 0; h < 2; ++h) {
            bf16x8 a0 = *(const bf16x8*)&As[(wm * 32 + col)      * LDT + h * 32 + g * 8];
            bf16x8 a1 = *(const bf16x8*)&As[(wm * 32 + 16 + col) * LDT + h * 32 + g * 8];
            bf16x8 b0 = *(const bf16x8*)&Bs[(wn * 32 + col)      * LDT + h * 32 + g * 8];
            bf16x8 b1 = *(const bf16x8*)&Bs[(wn * 32 + 16 + col) * LDT + h * 32 + g * 8];
            acc[0][0] = __builtin_amdgcn_mfma_f32_16x16x32_bf16(a0, b0, acc[0][0], 0, 0, 0);
            acc[0][1] = __builtin_amdgcn_mfma_f32_16x16x32_bf16(a0, b1, acc[0][1], 0, 0, 0);
            acc[1][0] = __builtin_amdgcn_mfma_f32_16x16x32_bf16(a1, b0, acc[1][0], 0, 0, 0);
            acc[1][1] = __builtin_amdgcn_mfma_f32_16x16x32_bf16(a1, b1, acc[1][1], 0, 0, 0);
        }
    }

    const float al = (MODE == 2) ? alphap[0] : 0.f;
    #pragma unroll
    for (int mi = 0; mi < 2; ++mi) {
        #pragma unroll
        for (int r = 0; r < 4; ++r) {
            const int row = r0 + wm * 32 + mi * 16 + g * 4 + r;
            #pragma unroll
            for (int ni = 0; ni < 2; ++ni) {
                const int cn = n0 + wn * 32 + ni * 16 + col;
                const float v = acc[mi][ni][r];
                if (MODE == 0) {
                    const float hjv = Hjf[(size_t)row * Hh + cn];
                    obf[(size_t)row * 2304 + cn] = (__bf16)v;
                    obf[(size_t)row * 2304 + 1536 + cn] = (__bf16)(v * hjv);
                } else if (MODE == 1) {
                    obf[(size_t)row * Oo + cn] = (__bf16)fmaxf(v + bias[cn], 0.f);
                } else {
                    of[(size_t)row * Hh + cn] = al * (v + bias[cn]);
                }
            }
        }
    }
}

// ---------------------------------------------------------------------------
extern "C" void kernel_launch(void* const* d_in, const int* in_sizes, int n_in,
                              void* d_out, int out_size, void* d_ws, size_t ws_size,
                              hipStream_t stream)
{
    const float* Hj  = (const float*)d_in[0];
    const float* Hi  = (const float*)d_in[1];
    const float* Wpj = (const float*)d_in[2];
    const float* Wpi = (const float*)d_in[3];
    const float* Ws1 = (const float*)d_in[4];
    const float* bs1 = (const float*)d_in[5];
    const float* ws2 = (const float*)d_in[6];
    const float* bs2 = (const float*)d_in[7];
    const float* Wv1 = (const float*)d_in[8];
    const float* bv1 = (const float*)d_in[9];
    const float* Wv2 = (const float*)d_in[10];
    const float* bv2 = (const float*)d_in[11];
    const float* alpha = (const float*)d_in[12];
    const int* mask  = (const int*)d_in[13];

    // workspace (float units) — all regions distinct
    float* ws = (float*)d_ws;
    float* Zj      = ws;                  // 49152
    float* Zip     = Zj + 49152;          // 65536  (2048x32 padded)
    float* WsT     = Zip + 65536;         // 9216
    float* probs_f = WsT + 9216;          // 524288
    float* HiT_f   = probs_f + 524288;    // 786432
    float* Wv2T_f  = HiT_f + 786432;      // 294912
    float* mhid_f  = Wv2T_f + 294912;     // 786432
    float* Acat_f  = mhid_f + 786432;     // 2359296
    float* Wv1T_f  = Acat_f + 2359296;    // 884736
    float* Bw_f    = Wv1T_f + 884736;     // 6291456 (25 MB bf16)
    // total ~48.2 MB

    __bf16* probs_bf = (__bf16*)probs_f;  // [2048][512]
    __bf16* HiT      = (__bf16*)HiT_f;    // [4][768][512]
    __bf16* Wv2T     = (__bf16*)Wv2T_f;   // [768][768]
    __bf16* mhid_bf  = (__bf16*)mhid_f;   // [2048][768]
    __bf16* Acat     = (__bf16*)Acat_f;   // [2048][2304]
    __bf16* Wv1T     = (__bf16*)Wv1T_f;   // [768][2304]
    __bf16* Bw       = (__bf16*)Bw_f;     // [2048][96][64]

    prep_kernel<<<dim3(8713), 256, 0, stream>>>(
        Hj, Hi, Wpj, Wpi, Wv1, Wv2, Ws1, Zj, Zip, WsT, HiT, Wv1T, Wv2T, Acat);
    wprep_kernel<<<dim3(2048), 256, 0, stream>>>(Zj, WsT, bs1, Bw);
    pair_kernel<<<dim3(Bb * Ss), 256, 0, stream>>>(
        Zj, Zip, Bw, ws2, bs2, mask, probs_bf);
    gemm_kernel<0><<<dim3(2048 / 64, Hh / 64), 256, 0, stream>>>(
        probs_bf, HiT, Hj, nullptr, nullptr, Acat, nullptr);
    gemm_kernel<1><<<dim3(2048 / 64, Oo / 64), 256, 0, stream>>>(
        Acat, Wv1T, nullptr, bv1, nullptr, mhid_bf, nullptr);
    gemm_kernel<2><<<dim3(2048 / 64, Hh / 64), 256, 0, stream>>>(
        mhid_bf, Wv2T, nullptr, bv2, alpha, nullptr, (float*)d_out);
}

// Round 11
// 182.719 us; speedup vs baseline: 1.1582x; 1.0575x over previous
//
#include <hip/hip_runtime.h>
#include <hip/hip_bf16.h>

#define Bb 4
#define Ss 512
#define Hh 768
#define Dd 24
#define Mm 96
#define Oo 768

typedef __bf16 bf16x8 __attribute__((ext_vector_type(8)));
typedef float f32x4 __attribute__((ext_vector_type(4)));

// ---------------------------------------------------------------------------
// Transpose tile helper: dst[c][r] = bf16(src[r][c]), one 32x32 tile.
// ---------------------------------------------------------------------------
__device__ __forceinline__ void transpose_tile(
    const float* __restrict__ s, __bf16* __restrict__ d,
    int R, int C, int bx, int by, float* smem, int tid)
{
    const int x = tid & 31, y = tid >> 5;
    const int c0 = bx * 32, r0 = by * 32;
    #pragma unroll
    for (int i = 0; i < 4; ++i)
        smem[(y + 8 * i) * 33 + x] = s[(size_t)(r0 + y + 8 * i) * C + c0 + x];
    __syncthreads();
    #pragma unroll
    for (int i = 0; i < 4; ++i)
        d[(size_t)(c0 + y + 8 * i) * R + r0 + x] = (__bf16)smem[x * 33 + (y + 8 * i)];
}

// ---------------------------------------------------------------------------
// prep_kernel (R8 structure, 4KB LDS): (a) proj -> Zj packed [row][24] and
// Zip padded [row][32] (rows 128B-aligned; slots 24..31 unused by pair's
// loads), (b) HiT, (c) Wv1T, (d) Wv2T, (e) Acat seg1 = bf16(Hj).
// blocks: [0,4096) proj | [4096,5632) HiT | [5632,7360) Wv1T |
//         [7360,7936) Wv2T | [7936,8704) hjconv
// ---------------------------------------------------------------------------
__global__ __launch_bounds__(256) void prep_kernel(
    const float* __restrict__ Hj, const float* __restrict__ Hi,
    const float* __restrict__ Wpj, const float* __restrict__ Wpi,
    const float* __restrict__ Wv1, const float* __restrict__ Wv2,
    float* __restrict__ Zj, float* __restrict__ Zip,
    __bf16* __restrict__ HiT, __bf16* __restrict__ Wv1T,
    __bf16* __restrict__ Wv2T, __bf16* __restrict__ Acat)
{
    __shared__ float smem[1088];
    const int bid = blockIdx.x;
    const int tid = threadIdx.x;

    if (bid < 4096) {
        const int row = bid & 2047;
        const int which = bid >> 11;
        const float* src = (which ? Hi : Hj) + (size_t)row * Hh;
        const float* W = which ? Wpi : Wpj;
        float* rowbuf = smem;
        float* partial = smem + 768;
        for (int i = tid; i < Hh; i += 256) rowbuf[i] = src[i];
        __syncthreads();
        if (tid < 192) {
            const int d = tid % Dd;
            const int c = tid / Dd;
            const int h0 = c * 96;
            float s = 0.f;
            #pragma unroll 4
            for (int h = h0; h < h0 + 96; ++h) s = fmaf(rowbuf[h], W[h * Dd + d], s);
            partial[c * Dd + d] = s;
        }
        __syncthreads();
        if (tid < Dd) {
            float s = 0.f;
            #pragma unroll
            for (int c = 0; c < 8; ++c) s += partial[c * Dd + tid];
            if (which) Zip[(size_t)row * 32 + tid] = s;
            else       Zj[(size_t)row * Dd + tid] = s;
        }
        if (which && tid >= Dd && tid < 32)
            Zip[(size_t)row * 32 + tid] = 0.0f;   // pad (never read by pair)
    } else if (bid < 5632) {
        int rem = bid - 4096;
        const int bz = rem / 384; rem %= 384;
        transpose_tile(Hi + (size_t)bz * Ss * Hh, HiT + (size_t)bz * Hh * Ss,
                       Ss, Hh, rem % 24, rem / 24, smem, tid);
    } else if (bid < 7360) {
        const int rem = bid - 5632;
        transpose_tile(Wv1, Wv1T, 3 * Hh, Oo, rem % 24, rem / 24, smem, tid);
    } else if (bid < 7936) {
        const int rem = bid - 7360;
        transpose_tile(Wv2, Wv2T, Oo, Hh, rem % 24, rem / 24, smem, tid);
    } else {
        const int idx = (bid - 7936) * 256 + tid;
        const int row = idx / 96, c8 = idx % 96;
        const float* s = Hj + (size_t)row * Hh + c8 * 8;
        const float4 u = *(const float4*)s;
        const float4 v = *(const float4*)(s + 4);
        bf16x8 o;
        o[0]=(__bf16)u.x; o[1]=(__bf16)u.y; o[2]=(__bf16)u.z; o[3]=(__bf16)u.w;
        o[4]=(__bf16)v.x; o[5]=(__bf16)v.y; o[6]=(__bf16)v.z; o[7]=(__bf16)v.w;
        *(bf16x8*)&Acat[(size_t)row * 2304 + Hh + c8 * 8] = o;
    }
}

// ---------------------------------------------------------------------------
// Kernel B (MFMA): per (b,p) block: logits over all 512 q + softmax -> bf16
// probs. Exact R4/R8 body; only change: Zi read from padded Zip (stride 32,
// 128B-aligned rows) instead of packed stride 24.
// ---------------------------------------------------------------------------
__global__ __launch_bounds__(256) void pair_kernel(
    const float* __restrict__ Zj, const float* __restrict__ Zip,
    const float* __restrict__ Ws1, const float* __restrict__ bs1,
    const float* __restrict__ ws2, const float* __restrict__ bs2p,
    const int* __restrict__ mask, __bf16* __restrict__ probs)
{
    const int bp = blockIdx.x;
    const int b  = bp >> 9;              // S = 512
    const int tid  = threadIdx.x;
    const int lane = tid & 63;
    const int wid  = tid >> 6;
    const int col  = lane & 15;
    const int g    = lane >> 4;

    __shared__ float zjall[Dd];
    __shared__ float rowadd[Mm];
    __shared__ float logitsl[Ss];
    __shared__ float red[8];

    if (tid < Dd) zjall[tid] = Zj[(size_t)bp * Dd + tid];
    __syncthreads();
    if (tid < Mm) {
        float s = bs1[tid];
        #pragma unroll
        for (int d = 0; d < Dd; ++d) s = fmaf(zjall[d], Ws1[d * Mm + tid], s);
        rowadd[tid] = s;
    }
    __syncthreads();

    float zj8[8];
    if (g < 3) {
        const float* zr = Zj + (size_t)bp * Dd + g * 8;
        const float4 u = *(const float4*)zr;
        const float4 v = *(const float4*)(zr + 4);
        zj8[0]=u.x; zj8[1]=u.y; zj8[2]=u.z; zj8[3]=u.w;
        zj8[4]=v.x; zj8[5]=v.y; zj8[6]=v.z; zj8[7]=v.w;
    } else {
        #pragma unroll
        for (int j = 0; j < 8; ++j) zj8[j] = 0.f;
    }

    bf16x8 bw[6][2];
    float ws2r[6];
    #pragma unroll
    for (int n = 0; n < 6; ++n) {
        const int m = n * 16 + col;
        ws2r[n] = ws2[m];
        bf16x8 b0, b1;
        if (g < 3) {
            #pragma unroll
            for (int j = 0; j < 8; ++j) {
                const int d = g * 8 + j;
                b0[j] = (__bf16)(fmaf(zj8[j], Ws1[(2 * Dd + d) * Mm + m],
                                      Ws1[(Dd + d) * Mm + m]));
                b1[j] = (__bf16)(Ws1[(3 * Dd + d) * Mm + m]);
            }
        } else {
            #pragma unroll
            for (int j = 0; j < 8; ++j) { b0[j] = (__bf16)0.f; b1[j] = (__bf16)0.f; }
            b0[0] = (__bf16)rowadd[m];
        }
        bw[n][0] = b0; bw[n][1] = b1;
    }

    const float* zib = Zip + (size_t)b * Ss * 32;

    #pragma unroll 2
    for (int t = 0; t < 8; ++t) {
        const int q0 = wid * 128 + t * 16;
        bf16x8 a0, a1;
        if (g < 3) {
            const float* zr = zib + (size_t)(q0 + col) * 32 + g * 8;
            const float4 u = *(const float4*)zr;
            const float4 v = *(const float4*)(zr + 4);
            a0[0]=(__bf16)u.x; a0[1]=(__bf16)u.y; a0[2]=(__bf16)u.z; a0[3]=(__bf16)u.w;
            a0[4]=(__bf16)v.x; a0[5]=(__bf16)v.y; a0[6]=(__bf16)v.z; a0[7]=(__bf16)v.w;
            a1[0]=(__bf16)fabsf(zj8[0]-u.x); a1[1]=(__bf16)fabsf(zj8[1]-u.y);
            a1[2]=(__bf16)fabsf(zj8[2]-u.z); a1[3]=(__bf16)fabsf(zj8[3]-u.w);
            a1[4]=(__bf16)fabsf(zj8[4]-v.x); a1[5]=(__bf16)fabsf(zj8[5]-v.y);
            a1[6]=(__bf16)fabsf(zj8[6]-v.z); a1[7]=(__bf16)fabsf(zj8[7]-v.w);
        } else {
            #pragma unroll
            for (int j = 0; j < 8; ++j) { a0[j] = (__bf16)0.f; a1[j] = (__bf16)0.f; }
            a0[0] = (__bf16)1.0f;
        }

        f32x4 acc[6];
        #pragma unroll
        for (int n = 0; n < 6; ++n) acc[n] = (f32x4){0.f, 0.f, 0.f, 0.f};
        #pragma unroll
        for (int n = 0; n < 6; ++n) {
            acc[n] = __builtin_amdgcn_mfma_f32_16x16x32_bf16(a0, bw[n][0], acc[n], 0, 0, 0);
            acc[n] = __builtin_amdgcn_mfma_f32_16x16x32_bf16(a1, bw[n][1], acc[n], 0, 0, 0);
        }

        float lsum[4] = {0.f, 0.f, 0.f, 0.f};
        #pragma unroll
        for (int n = 0; n < 6; ++n)
            #pragma unroll
            for (int r = 0; r < 4; ++r)
                lsum[r] = fmaf(fmaxf(acc[n][r], 0.f), ws2r[n], lsum[r]);
        #pragma unroll
        for (int off = 1; off <= 8; off <<= 1) {
            #pragma unroll
            for (int r = 0; r < 4; ++r) lsum[r] += __shfl_xor(lsum[r], off);
        }
        if (col == 0) {
            float4 o = {lsum[0], lsum[1], lsum[2], lsum[3]};
            *(float4*)&logitsl[q0 + g * 4] = o;
        }
    }
    __syncthreads();

    const float bs2v = bs2p[0];
    const int* mrow = mask + (size_t)b * Ss;
    float l0 = logitsl[tid]       + bs2v + (1.0f - (float)mrow[tid])       * (-3.402823466e+38f);
    float l1 = logitsl[tid + 256] + bs2v + (1.0f - (float)mrow[tid + 256]) * (-3.402823466e+38f);
    float vmax = fmaxf(l0, l1);
    #pragma unroll
    for (int off = 32; off > 0; off >>= 1) vmax = fmaxf(vmax, __shfl_xor(vmax, off));
    if (lane == 0) red[wid] = vmax;
    __syncthreads();
    const float mx = fmaxf(fmaxf(red[0], red[1]), fmaxf(red[2], red[3]));
    const float e0 = __expf(l0 - mx);
    const float e1 = __expf(l1 - mx);
    float vs = e0 + e1;
    #pragma unroll
    for (int off = 32; off > 0; off >>= 1) vs += __shfl_xor(vs, off);
    if (lane == 0) red[4 + wid] = vs;
    __syncthreads();
    const float inv = 1.0f / (red[4] + red[5] + red[6] + red[7]);
    __bf16* prow = probs + (size_t)bp * Ss;
    prow[tid] = (__bf16)(e0 * inv);
    prow[tid + 256] = (__bf16)(e1 * inv);
}

// ---------------------------------------------------------------------------
// bf16 MFMA GEMM (exact R4/R8 version), 64x64 tile, BK=64, LDS single-buffer
// + register prefetch. MODE 0: ctx -> Acat seg0 & seg2 (seg1 done in prep).
// MODE 1: mhid = relu(Acat@Wv1T + bv1). MODE 2: out = alpha*(mhid@Wv2T+bv2).
// ---------------------------------------------------------------------------
template<int MODE>
__global__ __launch_bounds__(256) void gemm_kernel(
    const __bf16* __restrict__ A, const __bf16* __restrict__ Bt,
    const float* __restrict__ Hjf, const float* __restrict__ bias,
    const float* __restrict__ alphap,
    __bf16* __restrict__ obf, float* __restrict__ of)
{
    constexpr int K = (MODE == 0) ? 512 : (MODE == 1) ? 2304 : 768;
    constexpr int NIT = K / 64;
    constexpr int LDT = 72;

    __shared__ __bf16 As[64 * LDT];
    __shared__ __bf16 Bs[64 * LDT];

    const int tid = threadIdx.x;
    const int lane = tid & 63;
    const int wid = tid >> 6;
    const int col = lane & 15, g = lane >> 4;
    const int wm = wid >> 1, wn = wid & 1;
    const int r0 = blockIdx.x * 64;
    const int n0 = blockIdx.y * 64;
    const __bf16* Btb = (MODE == 0) ? Bt + (size_t)(r0 >> 9) * (Hh * Ss) : Bt;

    const int srow = tid >> 2;
    const int sc8  = (tid & 3) * 16;
    const __bf16* ag = A   + (size_t)(r0 + srow) * K + sc8;
    const __bf16* bg = Btb + (size_t)(n0 + srow) * K + sc8;
    __bf16* asl = &As[srow * LDT + sc8];
    __bf16* bsl = &Bs[srow * LDT + sc8];

    bf16x8 ra0 = *(const bf16x8*)(ag);
    bf16x8 ra1 = *(const bf16x8*)(ag + 8);
    bf16x8 rb0 = *(const bf16x8*)(bg);
    bf16x8 rb1 = *(const bf16x8*)(bg + 8);

    f32x4 acc[2][2];
    #pragma unroll
    for (int mi = 0; mi < 2; ++mi)
        #pragma unroll
        for (int ni = 0; ni < 2; ++ni) acc[mi][ni] = (f32x4){0.f, 0.f, 0.f, 0.f};

    for (int it = 0; it < NIT; ++it) {
        __syncthreads();
        *(bf16x8*)(asl)     = ra0;
        *(bf16x8*)(asl + 8) = ra1;
        *(bf16x8*)(bsl)     = rb0;
        *(bf16x8*)(bsl + 8) = rb1;
        __syncthreads();
        if (it + 1 < NIT) {
            const int kk = (it + 1) * 64;
            ra0 = *(const bf16x8*)(ag + kk);
            ra1 = *(const bf16x8*)(ag + kk + 8);
            rb0 = *(const bf16x8*)(bg + kk);
            rb1 = *(const bf16x8*)(bg + kk + 8);
        }
        #pragma unroll
        for (int h = 0; h < 2; ++h) {
            bf16x8 a0 = *(const bf16x8*)&As[(wm * 32 + col)      * LDT + h * 32 + g * 8];
            bf16x8 a1 = *(const bf16x8*)&As[(wm * 32 + 16 + col) * LDT + h * 32 + g * 8];
            bf16x8 b0 = *(const bf16x8*)&Bs[(wn * 32 + col)      * LDT + h * 32 + g * 8];
            bf16x8 b1 = *(const bf16x8*)&Bs[(wn * 32 + 16 + col) * LDT + h * 32 + g * 8];
            acc[0][0] = __builtin_amdgcn_mfma_f32_16x16x32_bf16(a0, b0, acc[0][0], 0, 0, 0);
            acc[0][1] = __builtin_amdgcn_mfma_f32_16x16x32_bf16(a0, b1, acc[0][1], 0, 0, 0);
            acc[1][0] = __builtin_amdgcn_mfma_f32_16x16x32_bf16(a1, b0, acc[1][0], 0, 0, 0);
            acc[1][1] = __builtin_amdgcn_mfma_f32_16x16x32_bf16(a1, b1, acc[1][1], 0, 0, 0);
        }
    }

    const float al = (MODE == 2) ? alphap[0] : 0.f;
    #pragma unroll
    for (int mi = 0; mi < 2; ++mi) {
        #pragma unroll
        for (int r = 0; r < 4; ++r) {
            const int row = r0 + wm * 32 + mi * 16 + g * 4 + r;
            #pragma unroll
            for (int ni = 0; ni < 2; ++ni) {
                const int cn = n0 + wn * 32 + ni * 16 + col;
                const float v = acc[mi][ni][r];
                if (MODE == 0) {
                    const float hjv = Hjf[(size_t)row * Hh + cn];
                    obf[(size_t)row * 2304 + cn] = (__bf16)v;
                    obf[(size_t)row * 2304 + 1536 + cn] = (__bf16)(v * hjv);
                } else if (MODE == 1) {
                    obf[(size_t)row * Oo + cn] = (__bf16)fmaxf(v + bias[cn], 0.f);
                } else {
                    of[(size_t)row * Hh + cn] = al * (v + bias[cn]);
                }
            }
        }
    }
}

// ---------------------------------------------------------------------------
extern "C" void kernel_launch(void* const* d_in, const int* in_sizes, int n_in,
                              void* d_out, int out_size, void* d_ws, size_t ws_size,
                              hipStream_t stream)
{
    const float* Hj  = (const float*)d_in[0];
    const float* Hi  = (const float*)d_in[1];
    const float* Wpj = (const float*)d_in[2];
    const float* Wpi = (const float*)d_in[3];
    const float* Ws1 = (const float*)d_in[4];
    const float* bs1 = (const float*)d_in[5];
    const float* ws2 = (const float*)d_in[6];
    const float* bs2 = (const float*)d_in[7];
    const float* Wv1 = (const float*)d_in[8];
    const float* bv1 = (const float*)d_in[9];
    const float* Wv2 = (const float*)d_in[10];
    const float* bv2 = (const float*)d_in[11];
    const float* alpha = (const float*)d_in[12];
    const int* mask  = (const int*)d_in[13];

    // workspace (float units) — all regions distinct (R8 layout + padded Zip)
    float* ws = (float*)d_ws;
    float* Zj      = ws;                  // 49152
    float* Zip     = Zj + 49152;          // 65536 (2048x32, 128B rows)
    float* probs_f = Zip + 65536;         // 524288
    float* HiT_f   = probs_f + 524288;    // 786432
    float* Wv2T_f  = HiT_f + 786432;      // 294912
    float* mhid_f  = Wv2T_f + 294912;     // 786432
    float* Acat_f  = mhid_f + 786432;     // 2359296
    float* Wv1T_f  = Acat_f + 2359296;    // 884736
    // total 5,750,784 floats = 23.0 MB

    __bf16* probs_bf = (__bf16*)probs_f;  // [2048][512]
    __bf16* HiT      = (__bf16*)HiT_f;    // [4][768][512]
    __bf16* Wv2T     = (__bf16*)Wv2T_f;   // [768][768]
    __bf16* mhid_bf  = (__bf16*)mhid_f;   // [2048][768]
    __bf16* Acat     = (__bf16*)Acat_f;   // [2048][2304]
    __bf16* Wv1T     = (__bf16*)Wv1T_f;   // [768][2304]

    prep_kernel<<<dim3(8704), 256, 0, stream>>>(
        Hj, Hi, Wpj, Wpi, Wv1, Wv2, Zj, Zip, HiT, Wv1T, Wv2T, Acat);
    pair_kernel<<<dim3(Bb * Ss), 256, 0, stream>>>(
        Zj, Zip, Ws1, bs1, ws2, bs2, mask, probs_bf);
    gemm_kernel<0><<<dim3(2048 / 64, Hh / 64), 256, 0, stream>>>(
        probs_bf, HiT, Hj, nullptr, nullptr, Acat, nullptr);
    gemm_kernel<1><<<dim3(2048 / 64, Oo / 64), 256, 0, stream>>>(
        Acat, Wv1T, nullptr, bv1, nullptr, mhid_bf, nullptr);
    gemm_kernel<2><<<dim3(2048 / 64, Hh / 64), 256, 0, stream>>>(
        mhid_bf, Wv2T, nullptr, bv2, alpha, nullptr, (float*)d_out);
}

// Round 12
// 181.312 us; speedup vs baseline: 1.1672x; 1.0078x over previous
//
#include <hip/hip_runtime.h>
#include <hip/hip_bf16.h>

#define Bb 4
#define Ss 512
#define Hh 768
#define Dd 24
#define Mm 96
#define Oo 768

typedef __bf16 bf16x8 __attribute__((ext_vector_type(8)));
typedef float f32x4 __attribute__((ext_vector_type(4)));

// ---------------------------------------------------------------------------
// Transpose tile helper: dst[c][r] = bf16(src[r][c]), one 32x32 tile.
// ---------------------------------------------------------------------------
__device__ __forceinline__ void transpose_tile(
    const float* __restrict__ s, __bf16* __restrict__ d,
    int R, int C, int bx, int by, float* smem, int tid)
{
    const int x = tid & 31, y = tid >> 5;
    const int c0 = bx * 32, r0 = by * 32;
    #pragma unroll
    for (int i = 0; i < 4; ++i)
        smem[(y + 8 * i) * 33 + x] = s[(size_t)(r0 + y + 8 * i) * C + c0 + x];
    __syncthreads();
    #pragma unroll
    for (int i = 0; i < 4; ++i)
        d[(size_t)(c0 + y + 8 * i) * R + r0 + x] = (__bf16)smem[x * 33 + (y + 8 * i)];
}

// ---------------------------------------------------------------------------
// prep_kernel: fuses (a) proj (Zj,Zi), (b) HiT transpose, (c) Wv1T transpose,
// (d) Wv2T transpose, (e) Hj->bf16 into Acat seg1. One launch fills the
// machine instead of 5 serial small launches. 4KB LDS only (keep it that way:
// a 37KB branch-local array in R9 capped occupancy chip-wide).
// blocks: [0,4096) proj | [4096,5632) HiT | [5632,7360) Wv1T |
//         [7360,7936) Wv2T | [7936,8704) hjconv
// ---------------------------------------------------------------------------
__global__ __launch_bounds__(256) void prep_kernel(
    const float* __restrict__ Hj, const float* __restrict__ Hi,
    const float* __restrict__ Wpj, const float* __restrict__ Wpi,
    const float* __restrict__ Wv1, const float* __restrict__ Wv2,
    float* __restrict__ Zj, float* __restrict__ Zi,
    __bf16* __restrict__ HiT, __bf16* __restrict__ Wv1T,
    __bf16* __restrict__ Wv2T, __bf16* __restrict__ Acat)
{
    __shared__ float smem[1088];
    const int bid = blockIdx.x;
    const int tid = threadIdx.x;

    if (bid < 4096) {
        // ---- proj: Zj = H_j @ Wpj, Zi = H_i @ Wpi (both packed [row][24])
        const int row = bid & 2047;
        const int which = bid >> 11;
        const float* src = (which ? Hi : Hj) + (size_t)row * Hh;
        const float* W = which ? Wpi : Wpj;
        float* Z = which ? Zi : Zj;
        float* rowbuf = smem;            // [768]
        float* partial = smem + 768;     // [8][24]
        for (int i = tid; i < Hh; i += 256) rowbuf[i] = src[i];
        __syncthreads();
        if (tid < 192) {
            const int d = tid % Dd;
            const int c = tid / Dd;
            const int h0 = c * 96;
            float s = 0.f;
            #pragma unroll 4
            for (int h = h0; h < h0 + 96; ++h) s = fmaf(rowbuf[h], W[h * Dd + d], s);
            partial[c * Dd + d] = s;
        }
        __syncthreads();
        if (tid < Dd) {
            float s = 0.f;
            #pragma unroll
            for (int c = 0; c < 8; ++c) s += partial[c * Dd + tid];
            Z[(size_t)row * Dd + tid] = s;
        }
    } else if (bid < 5632) {
        // ---- HiT[b][h][q] = bf16(Hi[b][q][h]);  R=Ss, C=Hh, grid 24x16x4
        int rem = bid - 4096;
        const int bz = rem / 384; rem %= 384;
        transpose_tile(Hi + (size_t)bz * Ss * Hh, HiT + (size_t)bz * Hh * Ss,
                       Ss, Hh, rem % 24, rem / 24, smem, tid);
    } else if (bid < 7360) {
        // ---- Wv1T[o][k] = bf16(Wv1[k][o]);  R=2304, C=768, grid 24x72
        const int rem = bid - 5632;
        transpose_tile(Wv1, Wv1T, 3 * Hh, Oo, rem % 24, rem / 24, smem, tid);
    } else if (bid < 7936) {
        // ---- Wv2T[h][o] = bf16(Wv2[o][h]);  R=768, C=768, grid 24x24
        const int rem = bid - 7360;
        transpose_tile(Wv2, Wv2T, Oo, Hh, rem % 24, rem / 24, smem, tid);
    } else {
        // ---- hjconv: Acat seg1 = bf16(Hj)
        const int idx = (bid - 7936) * 256 + tid;   // [0, 2048*96)
        const int row = idx / 96, c8 = idx % 96;
        const float* s = Hj + (size_t)row * Hh + c8 * 8;
        const float4 u = *(const float4*)s;
        const float4 v = *(const float4*)(s + 4);
        bf16x8 o;
        o[0]=(__bf16)u.x; o[1]=(__bf16)u.y; o[2]=(__bf16)u.z; o[3]=(__bf16)u.w;
        o[4]=(__bf16)v.x; o[5]=(__bf16)v.y; o[6]=(__bf16)v.z; o[7]=(__bf16)v.w;
        *(bf16x8*)&Acat[(size_t)row * 2304 + Hh + c8 * 8] = o;
    }
}

// ---------------------------------------------------------------------------
// Kernel B (MFMA): per (b,p) block: logits over all 512 q + softmax -> bf16
// probs. R4-form — best of six measured variants (coalesced-Zip 52.4us,
// static-weight-expansion 58.2us, Bw-precompute ~= this + wprep overhead).
// ---------------------------------------------------------------------------
__global__ __launch_bounds__(256) void pair_kernel(
    const float* __restrict__ Zj, const float* __restrict__ Zi,
    const float* __restrict__ Ws1, const float* __restrict__ bs1,
    const float* __restrict__ ws2, const float* __restrict__ bs2p,
    const int* __restrict__ mask, __bf16* __restrict__ probs)
{
    const int bp = blockIdx.x;
    const int b  = bp >> 9;              // S = 512
    const int tid  = threadIdx.x;
    const int lane = tid & 63;
    const int wid  = tid >> 6;
    const int col  = lane & 15;
    const int g    = lane >> 4;

    __shared__ float zjall[Dd];
    __shared__ float rowadd[Mm];
    __shared__ float logitsl[Ss];
    __shared__ float red[8];

    if (tid < Dd) zjall[tid] = Zj[(size_t)bp * Dd + tid];
    __syncthreads();
    if (tid < Mm) {
        float s = bs1[tid];
        #pragma unroll
        for (int d = 0; d < Dd; ++d) s = fmaf(zjall[d], Ws1[d * Mm + tid], s);
        rowadd[tid] = s;
    }
    __syncthreads();

    float zj8[8];
    if (g < 3) {
        const float* zr = Zj + (size_t)bp * Dd + g * 8;
        const float4 u = *(const float4*)zr;
        const float4 v = *(const float4*)(zr + 4);
        zj8[0]=u.x; zj8[1]=u.y; zj8[2]=u.z; zj8[3]=u.w;
        zj8[4]=v.x; zj8[5]=v.y; zj8[6]=v.z; zj8[7]=v.w;
    } else {
        #pragma unroll
        for (int j = 0; j < 8; ++j) zj8[j] = 0.f;
    }

    bf16x8 bw[6][2];
    float ws2r[6];
    #pragma unroll
    for (int n = 0; n < 6; ++n) {
        const int m = n * 16 + col;
        ws2r[n] = ws2[m];
        bf16x8 b0, b1;
        if (g < 3) {
            #pragma unroll
            for (int j = 0; j < 8; ++j) {
                const int d = g * 8 + j;
                b0[j] = (__bf16)(fmaf(zj8[j], Ws1[(2 * Dd + d) * Mm + m],
                                      Ws1[(Dd + d) * Mm + m]));
                b1[j] = (__bf16)(Ws1[(3 * Dd + d) * Mm + m]);
            }
        } else {
            #pragma unroll
            for (int j = 0; j < 8; ++j) { b0[j] = (__bf16)0.f; b1[j] = (__bf16)0.f; }
            b0[0] = (__bf16)rowadd[m];
        }
        bw[n][0] = b0; bw[n][1] = b1;
    }

    const float* zib = Zi + (size_t)b * Ss * Dd;

    #pragma unroll 2
    for (int t = 0; t < 8; ++t) {
        const int q0 = wid * 128 + t * 16;
        bf16x8 a0, a1;
        if (g < 3) {
            const float* zr = zib + (size_t)(q0 + col) * Dd + g * 8;
            const float4 u = *(const float4*)zr;
            const float4 v = *(const float4*)(zr + 4);
            a0[0]=(__bf16)u.x; a0[1]=(__bf16)u.y; a0[2]=(__bf16)u.z; a0[3]=(__bf16)u.w;
            a0[4]=(__bf16)v.x; a0[5]=(__bf16)v.y; a0[6]=(__bf16)v.z; a0[7]=(__bf16)v.w;
            a1[0]=(__bf16)fabsf(zj8[0]-u.x); a1[1]=(__bf16)fabsf(zj8[1]-u.y);
            a1[2]=(__bf16)fabsf(zj8[2]-u.z); a1[3]=(__bf16)fabsf(zj8[3]-u.w);
            a1[4]=(__bf16)fabsf(zj8[4]-v.x); a1[5]=(__bf16)fabsf(zj8[5]-v.y);
            a1[6]=(__bf16)fabsf(zj8[6]-v.z); a1[7]=(__bf16)fabsf(zj8[7]-v.w);
        } else {
            #pragma unroll
            for (int j = 0; j < 8; ++j) { a0[j] = (__bf16)0.f; a1[j] = (__bf16)0.f; }
            a0[0] = (__bf16)1.0f;
        }

        f32x4 acc[6];
        #pragma unroll
        for (int n = 0; n < 6; ++n) acc[n] = (f32x4){0.f, 0.f, 0.f, 0.f};
        #pragma unroll
        for (int n = 0; n < 6; ++n) {
            acc[n] = __builtin_amdgcn_mfma_f32_16x16x32_bf16(a0, bw[n][0], acc[n], 0, 0, 0);
            acc[n] = __builtin_amdgcn_mfma_f32_16x16x32_bf16(a1, bw[n][1], acc[n], 0, 0, 0);
        }

        float lsum[4] = {0.f, 0.f, 0.f, 0.f};
        #pragma unroll
        for (int n = 0; n < 6; ++n)
            #pragma unroll
            for (int r = 0; r < 4; ++r)
                lsum[r] = fmaf(fmaxf(acc[n][r], 0.f), ws2r[n], lsum[r]);
        #pragma unroll
        for (int off = 1; off <= 8; off <<= 1) {
            #pragma unroll
            for (int r = 0; r < 4; ++r) lsum[r] += __shfl_xor(lsum[r], off);
        }
        if (col == 0) {
            float4 o = {lsum[0], lsum[1], lsum[2], lsum[3]};
            *(float4*)&logitsl[q0 + g * 4] = o;
        }
    }
    __syncthreads();

    const float bs2v = bs2p[0];
    const int* mrow = mask + (size_t)b * Ss;
    float l0 = logitsl[tid]       + bs2v + (1.0f - (float)mrow[tid])       * (-3.402823466e+38f);
    float l1 = logitsl[tid + 256] + bs2v + (1.0f - (float)mrow[tid + 256]) * (-3.402823466e+38f);
    float vmax = fmaxf(l0, l1);
    #pragma unroll
    for (int off = 32; off > 0; off >>= 1) vmax = fmaxf(vmax, __shfl_xor(vmax, off));
    if (lane == 0) red[wid] = vmax;
    __syncthreads();
    const float mx = fmaxf(fmaxf(red[0], red[1]), fmaxf(red[2], red[3]));
    const float e0 = __expf(l0 - mx);
    const float e1 = __expf(l1 - mx);
    float vs = e0 + e1;
    #pragma unroll
    for (int off = 32; off > 0; off >>= 1) vs += __shfl_xor(vs, off);
    if (lane == 0) red[4 + wid] = vs;
    __syncthreads();
    const float inv = 1.0f / (red[4] + red[5] + red[6] + red[7]);
    __bf16* prow = probs + (size_t)bp * Ss;
    prow[tid] = (__bf16)(e0 * inv);
    prow[tid + 256] = (__bf16)(e1 * inv);
}

// ---------------------------------------------------------------------------
// bf16 MFMA GEMM, 64x64 tile, BK=64, LDS single-buffer + register prefetch.
// MODE 0: ctx -> Acat seg0 & seg2 (seg1 done in prep).
// MODE 1: mhid = relu(Acat@Wv1T + bv1). MODE 2: out = alpha*(mhid@Wv2T+bv2).
// ---------------------------------------------------------------------------
template<int MODE>
__global__ __launch_bounds__(256) void gemm_kernel(
    const __bf16* __restrict__ A, const __bf16* __restrict__ Bt,
    const float* __restrict__ Hjf, const float* __restrict__ bias,
    const float* __restrict__ alphap,
    __bf16* __restrict__ obf, float* __restrict__ of)
{
    constexpr int K = (MODE == 0) ? 512 : (MODE == 1) ? 2304 : 768;
    constexpr int NIT = K / 64;
    constexpr int LDT = 72;

    __shared__ __bf16 As[64 * LDT];
    __shared__ __bf16 Bs[64 * LDT];

    const int tid = threadIdx.x;
    const int lane = tid & 63;
    const int wid = tid >> 6;
    const int col = lane & 15, g = lane >> 4;
    const int wm = wid >> 1, wn = wid & 1;
    const int r0 = blockIdx.x * 64;
    const int n0 = blockIdx.y * 64;
    const __bf16* Btb = (MODE == 0) ? Bt + (size_t)(r0 >> 9) * (Hh * Ss) : Bt;

    const int srow = tid >> 2;
    const int sc8  = (tid & 3) * 16;
    const __bf16* ag = A   + (size_t)(r0 + srow) * K + sc8;
    const __bf16* bg = Btb + (size_t)(n0 + srow) * K + sc8;
    __bf16* asl = &As[srow * LDT + sc8];
    __bf16* bsl = &Bs[srow * LDT + sc8];

    bf16x8 ra0 = *(const bf16x8*)(ag);
    bf16x8 ra1 = *(const bf16x8*)(ag + 8);
    bf16x8 rb0 = *(const bf16x8*)(bg);
    bf16x8 rb1 = *(const bf16x8*)(bg + 8);

    f32x4 acc[2][2];
    #pragma unroll
    for (int mi = 0; mi < 2; ++mi)
        #pragma unroll
        for (int ni = 0; ni < 2; ++ni) acc[mi][ni] = (f32x4){0.f, 0.f, 0.f, 0.f};

    for (int it = 0; it < NIT; ++it) {
        __syncthreads();
        *(bf16x8*)(asl)     = ra0;
        *(bf16x8*)(asl + 8) = ra1;
        *(bf16x8*)(bsl)     = rb0;
        *(bf16x8*)(bsl + 8) = rb1;
        __syncthreads();
        if (it + 1 < NIT) {
            const int kk = (it + 1) * 64;
            ra0 = *(const bf16x8*)(ag + kk);
            ra1 = *(const bf16x8*)(ag + kk + 8);
            rb0 = *(const bf16x8*)(bg + kk);
            rb1 = *(const bf16x8*)(bg + kk + 8);
        }
        #pragma unroll
        for (int h = 0; h < 2; ++h) {
            bf16x8 a0 = *(const bf16x8*)&As[(wm * 32 + col)      * LDT + h * 32 + g * 8];
            bf16x8 a1 = *(const bf16x8*)&As[(wm * 32 + 16 + col) * LDT + h * 32 + g * 8];
            bf16x8 b0 = *(const bf16x8*)&Bs[(wn * 32 + col)      * LDT + h * 32 + g * 8];
            bf16x8 b1 = *(const bf16x8*)&Bs[(wn * 32 + 16 + col) * LDT + h * 32 + g * 8];
            acc[0][0] = __builtin_amdgcn_mfma_f32_16x16x32_bf16(a0, b0, acc[0][0], 0, 0, 0);
            acc[0][1] = __builtin_amdgcn_mfma_f32_16x16x32_bf16(a0, b1, acc[0][1], 0, 0, 0);
            acc[1][0] = __builtin_amdgcn_mfma_f32_16x16x32_bf16(a1, b0, acc[1][0], 0, 0, 0);
            acc[1][1] = __builtin_amdgcn_mfma_f32_16x16x32_bf16(a1, b1, acc[1][1], 0, 0, 0);
        }
    }

    const float al = (MODE == 2) ? alphap[0] : 0.f;
    #pragma unroll
    for (int mi = 0; mi < 2; ++mi) {
        #pragma unroll
        for (int r = 0; r < 4; ++r) {
            const int row = r0 + wm * 32 + mi * 16 + g * 4 + r;
            #pragma unroll
            for (int ni = 0; ni < 2; ++ni) {
                const int cn = n0 + wn * 32 + ni * 16 + col;
                const float v = acc[mi][ni][r];
                if (MODE == 0) {
                    const float hjv = Hjf[(size_t)row * Hh + cn];
                    obf[(size_t)row * 2304 + cn] = (__bf16)v;
                    obf[(size_t)row * 2304 + 1536 + cn] = (__bf16)(v * hjv);
                } else if (MODE == 1) {
                    obf[(size_t)row * Oo + cn] = (__bf16)fmaxf(v + bias[cn], 0.f);
                } else {
                    of[(size_t)row * Hh + cn] = al * (v + bias[cn]);
                }
            }
        }
    }
}

// ---------------------------------------------------------------------------
extern "C" void kernel_launch(void* const* d_in, const int* in_sizes, int n_in,
                              void* d_out, int out_size, void* d_ws, size_t ws_size,
                              hipStream_t stream)
{
    const float* Hj  = (const float*)d_in[0];
    const float* Hi  = (const float*)d_in[1];
    const float* Wpj = (const float*)d_in[2];
    const float* Wpi = (const float*)d_in[3];
    const float* Ws1 = (const float*)d_in[4];
    const float* bs1 = (const float*)d_in[5];
    const float* ws2 = (const float*)d_in[6];
    const float* bs2 = (const float*)d_in[7];
    const float* Wv1 = (const float*)d_in[8];
    const float* bv1 = (const float*)d_in[9];
    const float* Wv2 = (const float*)d_in[10];
    const float* bv2 = (const float*)d_in[11];
    const float* alpha = (const float*)d_in[12];
    const int* mask  = (const int*)d_in[13];

    // workspace (float units) — all regions DISTINCT (no lifetime overlays)
    float* ws = (float*)d_ws;
    float* Zj      = ws;                  // 49152
    float* Zi      = Zj + 49152;          // 49152
    float* probs_f = Zi + 49152;          // 524288
    float* HiT_f   = probs_f + 524288;    // 786432
    float* Wv2T_f  = HiT_f + 786432;      // 294912
    float* mhid_f  = Wv2T_f + 294912;     // 786432
    float* Acat_f  = mhid_f + 786432;     // 2359296
    float* Wv1T_f  = Acat_f + 2359296;    // 884736
    // total 5,734,400 floats = 22.9 MB

    __bf16* probs_bf = (__bf16*)probs_f;  // [2048][512]
    __bf16* HiT      = (__bf16*)HiT_f;    // [4][768][512]
    __bf16* Wv2T     = (__bf16*)Wv2T_f;   // [768][768]
    __bf16* mhid_bf  = (__bf16*)mhid_f;   // [2048][768]
    __bf16* Acat     = (__bf16*)Acat_f;   // [2048][2304]
    __bf16* Wv1T     = (__bf16*)Wv1T_f;   // [768][2304]

    prep_kernel<<<dim3(8704), 256, 0, stream>>>(
        Hj, Hi, Wpj, Wpi, Wv1, Wv2, Zj, Zi, HiT, Wv1T, Wv2T, Acat);
    pair_kernel<<<dim3(Bb * Ss), 256, 0, stream>>>(
        Zj, Zi, Ws1, bs1, ws2, bs2, mask, probs_bf);
    gemm_kernel<0><<<dim3(2048 / 64, Hh / 64), 256, 0, stream>>>(
        probs_bf, HiT, Hj, nullptr, nullptr, Acat, nullptr);
    gemm_kernel<1><<<dim3(2048 / 64, Oo / 64), 256, 0, stream>>>(
        Acat, Wv1T, nullptr, bv1, nullptr, mhid_bf, nullptr);
    gemm_kernel<2><<<dim3(2048 / 64, Hh / 64), 256, 0, stream>>>(
        mhid_bf, Wv2T, nullptr, bv2, alpha, nullptr, (float*)d_out);
}